// Round 1
// baseline (582.191 us; speedup 1.0000x reference)
//
#include <hip/hip_runtime.h>

// VisualDepthAttention on MI355X (gfx950).
// Strategy: fused per-window kernel, all matmuls on bf16 MFMA 16x16x32 (fp32 accum).
// Kernel 1 (prep_weights): pack fp32 weights into bf16 MFMA-B-fragment-linear layout in d_ws.
//   Wcat: [K=288][N=784] = [Wqv*SCALE | Wkv | Wvv | Wqd*SCALE,Wkd,Wvd | zero-pad]
//   WoutP: [K=288][N=272] = Wout zero-padded.
//   Fragment layout: [kt][nt][lane][j] (8 bf16 = 16B per lane) -> one coalesced dwordx4 per B-frag.
// Kernel 2 (vda_attn): one block per window (2048 blocks, 256 threads = 4 waves, 152 KB LDS).

#define D1    257
#define NTOK  64
#define NH    8
#define KT    9      // K padded to 288 = 9*32
#define NT_CAT 49    // Wcat N = 784 = 49*16
#define NT_OUT 17    // Wout N = 272 = 17*16
#define SCALE 0.17677669529663687f

// LDS layout (byte offsets). Total 152320 <= 163840.
#define XS_OFF    0        // x window bf16 [64][296] (K-padded); later overlaid by outcat [64][288]
#define XS_STRIDE 296
#define OC_STRIDE 288
#define QS_OFF    37888    // qv bf16 [64][264]
#define QK_STRIDE 264
#define KS_OFF    71680    // kv bf16 [64][264]
#define VS_OFF    105472   // vv^T bf16 [256][72]
#define VS_STRIDE 72
#define AT_OFF    142336   // per-wave attn bf16: 4 x [16][72]
#define AT_STRIDE 72
#define QD_OFF    151552   // fp32[64]
#define KD_OFF    151808   // fp32[64]
#define VD_OFF    152064   // fp32[64]
#define LDS_SIZE  152320

#define WCAT_ELEMS (KT * NT_CAT * 512)   // 225792 bf16
#define WOUT_ELEMS (KT * NT_OUT * 512)   // 78336 bf16

using bf16x8 = __attribute__((ext_vector_type(8))) short;
using s16x4  = __attribute__((ext_vector_type(4))) short;
using f32x4  = __attribute__((ext_vector_type(4))) float;

__device__ __forceinline__ short f2b(float f) {
  unsigned u = __float_as_uint(f);
  u = (u + 0x7FFFu + ((u >> 16) & 1u)) >> 16;   // RNE
  return (short)u;
}

__device__ __forceinline__ f32x4 mfma16(bf16x8 a, bf16x8 b, f32x4 c) {
  return __builtin_amdgcn_mfma_f32_16x16x32_bf16(a, b, c, 0, 0, 0);
}

__global__ void prep_weights(const float* __restrict__ Wqv, const float* __restrict__ Wkv,
                             const float* __restrict__ Wvv, const float* __restrict__ Wqd,
                             const float* __restrict__ Wkd, const float* __restrict__ Wvd,
                             const float* __restrict__ Wout,
                             short* __restrict__ wcatp, short* __restrict__ woutp) {
  int idx = blockIdx.x * 256 + threadIdx.x;   // grid sized exactly: WCAT_ELEMS + WOUT_ELEMS
  if (idx < WCAT_ELEMS) {
    int j = idx & 7, lane = (idx >> 3) & 63, rest = idx >> 9;
    int nt = rest % NT_CAT, kt = rest / NT_CAT;
    int k = 32 * kt + (lane >> 4) * 8 + j;
    int n = 16 * nt + (lane & 15);
    float v = 0.f;
    if (k < D1) {
      if (n < 256)       v = Wqv[k * 256 + n] * SCALE;
      else if (n < 512)  v = Wkv[k * 256 + (n - 256)];
      else if (n < 768)  v = Wvv[k * 256 + (n - 512)];
      else if (n == 768) v = Wqd[k] * SCALE;
      else if (n == 769) v = Wkd[k];
      else if (n == 770) v = Wvd[k];
    }
    wcatp[idx] = f2b(v);
  } else {
    int i2 = idx - WCAT_ELEMS;
    int j = i2 & 7, lane = (i2 >> 3) & 63, rest = i2 >> 9;
    int nt = rest % NT_OUT, kt = rest / NT_OUT;
    int k = 32 * kt + (lane >> 4) * 8 + j;
    int n = 16 * nt + (lane & 15);
    float v = (k < D1 && n < D1) ? Wout[k * D1 + n] : 0.f;
    woutp[i2] = f2b(v);
  }
}

__global__ __launch_bounds__(256, 1)
void vda_attn(const float* __restrict__ x, const short* __restrict__ wcatp,
              const short* __restrict__ woutp, float* __restrict__ out) {
  extern __shared__ char smem[];
  short* xs  = (short*)(smem + XS_OFF);
  short* qs  = (short*)(smem + QS_OFF);
  short* ks  = (short*)(smem + KS_OFF);
  short* vs  = (short*)(smem + VS_OFF);
  short* at  = (short*)(smem + AT_OFF);
  float* qd_s = (float*)(smem + QD_OFF);
  float* kd_s = (float*)(smem + KD_OFF);
  float* vd_s = (float*)(smem + VD_OFF);
  short* oc = xs;  // outcat [64][288] overlays xs after projections

  const int tid  = threadIdx.x;
  const int lane = tid & 63;
  const int w    = tid >> 6;        // wave id 0..3
  const int m    = lane & 15;
  const int q    = lane >> 4;
  const int q8   = q * 8;
  const int win  = blockIdx.x;

  // ---- Phase A: stage x window (64x257 fp32) -> xs bf16, zero-pad K cols 257..295
  for (int i = tid; i < 64 * 40; i += 256) {
    int r = i / 40, c = 256 + (i % 40);
    if (c > 256) xs[r * XS_STRIDE + c] = 0;   // col 256 is real data, skip
  }
  {
    const float4* xw4 = (const float4*)(x + (size_t)win * (NTOK * D1));
    for (int it = 0; it < 17; ++it) {
      int f4 = tid + it * 256;
      if (f4 < 4112) {                         // 16448 floats = 4112 float4
        float4 v = xw4[f4];
        float vals[4] = {v.x, v.y, v.z, v.w};
        int o0 = f4 * 4;
#pragma unroll
        for (int jj = 0; jj < 4; ++jj) {
          int o = o0 + jj;
          int r = o / D1;
          int c = o - r * D1;
          xs[r * XS_STRIDE + c] = f2b(vals[jj]);
        }
      }
    }
  }
  __syncthreads();

  // ---- Phase B: QKV + depth projections. C = xs[64x288] @ Wcat[288x784].
  // A-frags (xs) cached in regs: 4 mtiles x 9 ktiles x 4 VGPR = 144 VGPRs.
  {
    bf16x8 af[4][KT];
#pragma unroll
    for (int mt = 0; mt < 4; ++mt)
#pragma unroll
      for (int kt = 0; kt < KT; ++kt)
        af[mt][kt] = *(const bf16x8*)&xs[(16 * mt + m) * XS_STRIDE + 32 * kt + q8];

    for (int nt = w; nt < NT_CAT; nt += 4) {   // wave w owns ntiles w, w+4, ...
      f32x4 acc[4];
#pragma unroll
      for (int mt = 0; mt < 4; ++mt) acc[mt] = f32x4{0.f, 0.f, 0.f, 0.f};
      const short* wp = wcatp + ((size_t)nt * 64 + lane) * 8;
#pragma unroll
      for (int kt = 0; kt < KT; ++kt) {
        bf16x8 bfr = *(const bf16x8*)(wp + (size_t)kt * (NT_CAT * 512));
#pragma unroll
        for (int mt = 0; mt < 4; ++mt)
          acc[mt] = mfma16(af[mt][kt], bfr, acc[mt]);
      }
      int c = nt * 16 + m;
      if (c < 256) {                 // qv (SCALE folded into weights)
#pragma unroll
        for (int mt = 0; mt < 4; ++mt)
#pragma unroll
          for (int r = 0; r < 4; ++r)
            qs[(16 * mt + 4 * q + r) * QK_STRIDE + c] = f2b(acc[mt][r]);
      } else if (c < 512) {          // kv
#pragma unroll
        for (int mt = 0; mt < 4; ++mt)
#pragma unroll
          for (int r = 0; r < 4; ++r)
            ks[(16 * mt + 4 * q + r) * QK_STRIDE + (c - 256)] = f2b(acc[mt][r]);
      } else if (c < 768) {          // vv, stored transposed vs[d][token]
        int d = c - 512;
#pragma unroll
        for (int mt = 0; mt < 4; ++mt) {
          s16x4 pk;
#pragma unroll
          for (int r = 0; r < 4; ++r) pk[r] = f2b(acc[mt][r]);
          *(s16x4*)&vs[d * VS_STRIDE + 16 * mt + 4 * q] = pk;   // 4 consecutive tokens
        }
      } else {                       // depth projections qd/kd/vd (fp32, cols 768..770)
        if (m < 3) {
          float* dst = (m == 0) ? qd_s : (m == 1) ? kd_s : vd_s;
#pragma unroll
          for (int mt = 0; mt < 4; ++mt)
#pragma unroll
            for (int r = 0; r < 4; ++r)
              dst[16 * mt + 4 * q + r] = acc[mt][r];
        }
      }
    }
  }
  __syncthreads();

  // ---- Phase C: per-head sim -> sigmoid gate -> softmax -> PV. Wave w owns rows 16w..16w+15.
  // Zero outcat pad cols 256..287 for my rows (out_d overwrites col 256 later, same wave => ordered).
  {
    int row = 16 * w + m;
#pragma unroll
    for (int i = 0; i < 8; ++i)
      oc[row * OC_STRIDE + 256 + q8 + i] = 0;
  }

  float gate[4][4];   // [ntile j][reg r]: sigmoid(qd[t]*kd[j]), head-independent
  float ssum[4][4];   // running sum over heads of sim_m (for attn_d)
  {
    float qd_r[4], kd_c[4];
#pragma unroll
    for (int r = 0; r < 4; ++r) qd_r[r] = qd_s[16 * w + 4 * q + r];
#pragma unroll
    for (int nt = 0; nt < 4; ++nt) kd_c[nt] = kd_s[16 * nt + m];
#pragma unroll
    for (int nt = 0; nt < 4; ++nt)
#pragma unroll
      for (int r = 0; r < 4; ++r) {
        float t = qd_r[r] * kd_c[nt];
        gate[nt][r] = 1.f / (1.f + __expf(-t));
        ssum[nt][r] = 0.f;
      }
  }

  short* atw = at + w * (16 * AT_STRIDE);  // per-wave attn buffer [16][72]

  for (int h = 0; h < NH; ++h) {
    // sim = q[rows 16w..] @ k^T  (K = 32 head dims, one MFMA per ntile)
    bf16x8 aq = *(const bf16x8*)&qs[(16 * w + m) * QK_STRIDE + 32 * h + q8];
    f32x4 sv[4];
#pragma unroll
    for (int nt = 0; nt < 4; ++nt) {
      bf16x8 bk = *(const bf16x8*)&ks[(16 * nt + m) * QK_STRIDE + 32 * h + q8];
      f32x4 z = {0.f, 0.f, 0.f, 0.f};
      sv[nt] = mfma16(aq, bk, z);
    }
    // gate, accumulate head-sum, row softmax (rows live in 16-lane groups, shfl-reduce)
    float sm[4][4], mx[4], sum[4];
#pragma unroll
    for (int r = 0; r < 4; ++r) mx[r] = -3.4e38f;
#pragma unroll
    for (int nt = 0; nt < 4; ++nt)
#pragma unroll
      for (int r = 0; r < 4; ++r) {
        float s = sv[nt][r] * gate[nt][r];
        ssum[nt][r] += s;
        sm[nt][r] = s;
        mx[r] = fmaxf(mx[r], s);
      }
#pragma unroll
    for (int r = 0; r < 4; ++r) {
#pragma unroll
      for (int msk = 1; msk < 16; msk <<= 1)
        mx[r] = fmaxf(mx[r], __shfl_xor(mx[r], msk));
      sum[r] = 0.f;
    }
#pragma unroll
    for (int nt = 0; nt < 4; ++nt)
#pragma unroll
      for (int r = 0; r < 4; ++r) {
        float p = __expf(sm[nt][r] - mx[r]);
        sm[nt][r] = p;
        sum[r] += p;
      }
#pragma unroll
    for (int r = 0; r < 4; ++r) {
#pragma unroll
      for (int msk = 1; msk < 16; msk <<= 1)
        sum[r] += __shfl_xor(sum[r], msk);
      sum[r] = 1.f / sum[r];
    }
    // write attn (bf16) to wave-local buffer in A-operand-friendly row-major
#pragma unroll
    for (int nt = 0; nt < 4; ++nt)
#pragma unroll
      for (int r = 0; r < 4; ++r)
        atw[(4 * q + r) * AT_STRIDE + 16 * nt + m] = f2b(sm[nt][r] * sum[r]);

    // PV: out_v[rows, 32h..32h+31] = attn(16x64) @ vv(64x32); vs holds vv^T
    bf16x8 a0 = *(const bf16x8*)&atw[m * AT_STRIDE + q8];
    bf16x8 a1 = *(const bf16x8*)&atw[m * AT_STRIDE + 32 + q8];
#pragma unroll
    for (int ntp = 0; ntp < 2; ++ntp) {
      int drow = 32 * h + 16 * ntp + m;
      bf16x8 bv0 = *(const bf16x8*)&vs[drow * VS_STRIDE + q8];
      bf16x8 bv1 = *(const bf16x8*)&vs[drow * VS_STRIDE + 32 + q8];
      f32x4 o = {0.f, 0.f, 0.f, 0.f};
      o = mfma16(a0, bv0, o);
      o = mfma16(a1, bv1, o);
#pragma unroll
      for (int r = 0; r < 4; ++r)
        oc[(16 * w + 4 * q + r) * OC_STRIDE + 32 * h + 16 * ntp + m] = f2b(o[r]);
    }
  }

  // attn_d = softmax(ssum), out_d = attn_d @ vd -> outcat col 256
  {
    float mx[4], sum[4], pd[4][4];
#pragma unroll
    for (int r = 0; r < 4; ++r) mx[r] = -3.4e38f;
#pragma unroll
    for (int nt = 0; nt < 4; ++nt)
#pragma unroll
      for (int r = 0; r < 4; ++r) mx[r] = fmaxf(mx[r], ssum[nt][r]);
#pragma unroll
    for (int r = 0; r < 4; ++r) {
#pragma unroll
      for (int msk = 1; msk < 16; msk <<= 1)
        mx[r] = fmaxf(mx[r], __shfl_xor(mx[r], msk));
      sum[r] = 0.f;
    }
#pragma unroll
    for (int nt = 0; nt < 4; ++nt)
#pragma unroll
      for (int r = 0; r < 4; ++r) {
        pd[nt][r] = __expf(ssum[nt][r] - mx[r]);
        sum[r] += pd[nt][r];
      }
#pragma unroll
    for (int r = 0; r < 4; ++r) {
#pragma unroll
      for (int msk = 1; msk < 16; msk <<= 1)
        sum[r] += __shfl_xor(sum[r], msk);
      sum[r] = 1.f / sum[r];
    }
    float vd_c[4];
#pragma unroll
    for (int nt = 0; nt < 4; ++nt) vd_c[nt] = vd_s[16 * nt + m];
    float ov[4] = {0.f, 0.f, 0.f, 0.f};
#pragma unroll
    for (int nt = 0; nt < 4; ++nt)
#pragma unroll
      for (int r = 0; r < 4; ++r) ov[r] += pd[nt][r] * vd_c[nt];
#pragma unroll
    for (int r = 0; r < 4; ++r) {
#pragma unroll
      for (int msk = 1; msk < 16; msk <<= 1)
        ov[r] += __shfl_xor(ov[r], msk);
    }
    if (m == 0) {
#pragma unroll
      for (int r = 0; r < 4; ++r)
        oc[(16 * w + 4 * q + r) * OC_STRIDE + 256] = f2b(ov[r] * sum[r]);
    }
  }
  __syncthreads();

  // ---- Phase D: out = outcat[64x288] @ Wout[288x272], store fp32 (n < 257)
  for (int nt = w; nt < NT_OUT; nt += 4) {
    f32x4 acc[4];
#pragma unroll
    for (int mt = 0; mt < 4; ++mt) acc[mt] = f32x4{0.f, 0.f, 0.f, 0.f};
#pragma unroll
    for (int kt = 0; kt < KT; ++kt) {
      bf16x8 bw = *(const bf16x8*)(woutp + ((size_t)(kt * NT_OUT + nt) * 64 + lane) * 8);
#pragma unroll
      for (int mt = 0; mt < 4; ++mt) {
        bf16x8 ao = *(const bf16x8*)&oc[(16 * mt + m) * OC_STRIDE + 32 * kt + q8];
        acc[mt] = mfma16(ao, bw, acc[mt]);
      }
    }
    int n = 16 * nt + m;
    if (n < D1) {
#pragma unroll
      for (int mt = 0; mt < 4; ++mt)
#pragma unroll
        for (int r = 0; r < 4; ++r)
          out[((size_t)win * NTOK + 16 * mt + 4 * q + r) * D1 + n] = acc[mt][r];
    }
  }
}

extern "C" void kernel_launch(void* const* d_in, const int* in_sizes, int n_in,
                              void* d_out, int out_size, void* d_ws, size_t ws_size,
                              hipStream_t stream) {
  (void)n_in; (void)out_size; (void)ws_size;
  const float* x    = (const float*)d_in[0];
  const float* Wqv  = (const float*)d_in[1];
  const float* Wkv  = (const float*)d_in[2];
  const float* Wvv  = (const float*)d_in[3];
  const float* Wqd  = (const float*)d_in[4];
  const float* Wkd  = (const float*)d_in[5];
  const float* Wvd  = (const float*)d_in[6];
  const float* Wout = (const float*)d_in[7];
  float* out = (float*)d_out;

  short* wcatp = (short*)d_ws;                  // 225792 bf16
  short* woutp = wcatp + WCAT_ELEMS;            // 78336 bf16 (total ws use ~608 KB)

  int nwin = in_sizes[0] / (NTOK * D1);         // 2048

  // >64KB dynamic LDS opt-in (host-side attribute set; graph-capture safe, idempotent)
  hipFuncSetAttribute((const void*)vda_attn, hipFuncAttributeMaxDynamicSharedMemorySize, LDS_SIZE);

  int prep_blocks = (WCAT_ELEMS + WOUT_ELEMS) / 256;   // 1188, exact
  prep_weights<<<prep_blocks, 256, 0, stream>>>(Wqv, Wkv, Wvv, Wqd, Wkd, Wvd, Wout, wcatp, woutp);
  vda_attn<<<nwin, 256, LDS_SIZE, stream>>>(x, wcatp, woutp, out);
}

// Round 2
// 563.118 us; speedup vs baseline: 1.0339x; 1.0339x over previous
//
#include <hip/hip_runtime.h>

// VisualDepthAttention on MI355X (gfx950) — round 2.
// R1 post-mortem: 424 us, MfmaUtil 8.4%, VALUBusy 17.7%, Occupancy 11.6% (=1 wave/SIMD,
// 152KB LDS -> 1 block/CU, 4-wave block). Pure latency exposure.
// R2: 1024-thread block (16 waves -> 4 waves/SIMD, 50% occupancy), VGPR-capped-at-128-safe
// structure: kt-outer GEMM accumulation (acc in regs, A-frags 1x/kt, B-frags streamed, no
// duplicate L2 reads), vs stored B-fragment-linear (conflict-free PV reads), head-sum via
// LDS fp32 atomics. 5 barriers total.

#define D1    257
#define NTOK  64
#define NH    8
#define KT    9      // K padded to 288 = 9*32
#define NT_CAT 49    // Wcat N = 784 = 49*16
#define NT_OUT 17    // Wout N = 272 = 17*16
#define SCALE 0.17677669529663687f

// LDS layout (byte offsets). Total 156,672 <= 163,840.
#define XS_OFF    0        // x bf16 [64][296]; overlaid by outcat [64][296] in phases C/D
#define XS_STRIDE 296
#define OC_STRIDE 296
#define QS_OFF    37888    // qv bf16 [64][264] (33,792); overlaid by at: 16 waves x [16][68] (34,816)
#define QK_STRIDE 264
#define AT_STRIDE 68
#define KS_OFF    72704    // kv bf16 [64][264] (33,792)
#define VS_OFF    106496   // vv B-frag-linear: 32 frags x 512 bf16 (32,768)
#define DS_OFF    139264   // dsum fp32 [64][65] (16,640)
#define DS_STRIDE 65
#define QD_OFF    155904   // fp32[64]
#define KD_OFF    156160   // fp32[64]
#define VD_OFF    156416   // fp32[64]
#define LDS_SIZE  156672

#define WCAT_ELEMS (KT * NT_CAT * 512)   // 225792 bf16
#define WOUT_ELEMS (KT * NT_OUT * 512)   // 78336 bf16

using bf16x8 = __attribute__((ext_vector_type(8))) short;
using s16x4  = __attribute__((ext_vector_type(4))) short;
using f32x4  = __attribute__((ext_vector_type(4))) float;

__device__ __forceinline__ short f2b(float f) {
  unsigned u = __float_as_uint(f);
  u = (u + 0x7FFFu + ((u >> 16) & 1u)) >> 16;   // RNE
  return (short)u;
}

__device__ __forceinline__ f32x4 mfma16(bf16x8 a, bf16x8 b, f32x4 c) {
  return __builtin_amdgcn_mfma_f32_16x16x32_bf16(a, b, c, 0, 0, 0);
}

__global__ void prep_weights(const float* __restrict__ Wqv, const float* __restrict__ Wkv,
                             const float* __restrict__ Wvv, const float* __restrict__ Wqd,
                             const float* __restrict__ Wkd, const float* __restrict__ Wvd,
                             const float* __restrict__ Wout,
                             short* __restrict__ wcatp, short* __restrict__ woutp) {
  int idx = blockIdx.x * 256 + threadIdx.x;
  if (idx < WCAT_ELEMS) {
    int j = idx & 7, lane = (idx >> 3) & 63, rest = idx >> 9;
    int nt = rest % NT_CAT, kt = rest / NT_CAT;
    int k = 32 * kt + (lane >> 4) * 8 + j;
    int n = 16 * nt + (lane & 15);
    float v = 0.f;
    if (k < D1) {
      if (n < 256)       v = Wqv[k * 256 + n] * SCALE;
      else if (n < 512)  v = Wkv[k * 256 + (n - 256)];
      else if (n < 768)  v = Wvv[k * 256 + (n - 512)];
      else if (n == 768) v = Wqd[k] * SCALE;
      else if (n == 769) v = Wkd[k];
      else if (n == 770) v = Wvd[k];
    }
    wcatp[idx] = f2b(v);
  } else {
    int i2 = idx - WCAT_ELEMS;
    int j = i2 & 7, lane = (i2 >> 3) & 63, rest = i2 >> 9;
    int nt = rest % NT_OUT, kt = rest / NT_OUT;
    int k = 32 * kt + (lane >> 4) * 8 + j;
    int n = 16 * nt + (lane & 15);
    float v = (k < D1 && n < D1) ? Wout[k * D1 + n] : 0.f;
    woutp[i2] = f2b(v);
  }
}

__global__ __launch_bounds__(1024)
void vda_attn(const float* __restrict__ x, const short* __restrict__ wcatp,
              const short* __restrict__ woutp, float* __restrict__ out) {
  extern __shared__ char smem[];
  short* xs  = (short*)(smem + XS_OFF);
  short* qs  = (short*)(smem + QS_OFF);
  short* ks  = (short*)(smem + KS_OFF);
  short* vs  = (short*)(smem + VS_OFF);
  float* dsum = (float*)(smem + DS_OFF);
  float* qd_s = (float*)(smem + QD_OFF);
  float* kd_s = (float*)(smem + KD_OFF);
  float* vd_s = (float*)(smem + VD_OFF);
  short* oc = xs;   // outcat overlays xs (same stride 296)

  const int tid  = threadIdx.x;
  const int lane = tid & 63;
  const int w    = tid >> 6;        // wave id 0..15
  const int m    = lane & 15;
  const int q    = lane >> 4;
  const int q8   = q * 8;
  const int win  = blockIdx.x;

  // ---- Phase A: stage x (64x257 fp32 -> bf16), zero K-pad cols, zero dsum.
  for (int i = tid; i < 64 * 39; i += 1024) {
    int r = i / 39, c = 257 + (i % 39);
    xs[r * XS_STRIDE + c] = 0;
  }
  for (int i = tid; i < 64 * DS_STRIDE; i += 1024) dsum[i] = 0.f;
  {
    const float4* xw4 = (const float4*)(x + (size_t)win * (NTOK * D1));
    for (int f4 = tid; f4 < 4112; f4 += 1024) {
      float4 v = xw4[f4];
      float vals[4] = {v.x, v.y, v.z, v.w};
      int o0 = f4 * 4;
      int r0 = o0 / D1, c0 = o0 - r0 * D1;
#pragma unroll
      for (int jj = 0; jj < 4; ++jj) {
        int c = c0 + jj, r = r0;
        if (c >= D1) { c -= D1; r += 1; }
        xs[r * XS_STRIDE + c] = f2b(vals[jj]);
      }
    }
  }
  __syncthreads();   // S1

  // ---- Phase B: C = xs[64x288] @ Wcat[288x784]. kt-outer, acc resident (64 VGPRs).
  // Wave w owns nt in {w, w+16, w+32, w+48}.
  {
    f32x4 acc[4][4];
#pragma unroll
    for (int t = 0; t < 4; ++t)
#pragma unroll
      for (int mt = 0; mt < 4; ++mt) acc[t][mt] = f32x4{0.f, 0.f, 0.f, 0.f};

    for (int kt = 0; kt < KT; ++kt) {
      bf16x8 af[4];
#pragma unroll
      for (int mt = 0; mt < 4; ++mt)
        af[mt] = *(const bf16x8*)&xs[(16 * mt + m) * XS_STRIDE + 32 * kt + q8];
#pragma unroll
      for (int t = 0; t < 4; ++t) {
        int nt = w + 16 * t;
        if (nt < NT_CAT) {
          bf16x8 bfr = *(const bf16x8*)(wcatp + ((size_t)(kt * NT_CAT + nt) * 64 + lane) * 8);
#pragma unroll
          for (int mt = 0; mt < 4; ++mt)
            acc[t][mt] = mfma16(af[mt], bfr, acc[t][mt]);
        }
      }
    }
    // epilogue: scatter to qs / ks / vs-frag / depth
#pragma unroll
    for (int t = 0; t < 4; ++t) {
      int nt = w + 16 * t;
      if (nt >= NT_CAT) continue;
      int c = nt * 16 + m;
      if (c < 256) {
#pragma unroll
        for (int mt = 0; mt < 4; ++mt)
#pragma unroll
          for (int r = 0; r < 4; ++r)
            qs[(16 * mt + 4 * q + r) * QK_STRIDE + c] = f2b(acc[t][mt][r]);
      } else if (c < 512) {
#pragma unroll
        for (int mt = 0; mt < 4; ++mt)
#pragma unroll
          for (int r = 0; r < 4; ++r)
            ks[(16 * mt + 4 * q + r) * QK_STRIDE + (c - 256)] = f2b(acc[t][mt][r]);
      } else if (c < 768) {
        // vs B-frag-linear: element (token=16mt+4q+r, d=c-512) ->
        // frag = (d>>4)*2 + (token>>5), slot = (((token>>3)&3)*16 + (d&15))*8 + (token&7)
#pragma unroll
        for (int mt = 0; mt < 4; ++mt) {
          int frag = (nt - 32) * 2 + (mt >> 1);
          int q2 = (2 * mt + (q >> 1)) & 3;
          int j0 = 4 * (q & 1);
          s16x4 pk;
#pragma unroll
          for (int r = 0; r < 4; ++r) pk[r] = f2b(acc[t][mt][r]);
          *(s16x4*)&vs[frag * 512 + (q2 * 16 + m) * 8 + j0] = pk;
        }
      } else {                       // nt==48: depth cols 768..770
        if (m < 3) {
          float* dst = (m == 0) ? qd_s : (m == 1) ? kd_s : vd_s;
#pragma unroll
          for (int mt = 0; mt < 4; ++mt)
#pragma unroll
            for (int r = 0; r < 4; ++r)
              dst[16 * mt + 4 * q + r] = acc[t][mt][r];
        }
      }
    }
  }
  __syncthreads();   // S2

  // ---- Phase C: wave = (rw = w&3 row tile, hp = w>>2 head pair {2hp, 2hp+1}).
  const int rw = w & 3;
  const int hp = w >> 2;

  bf16x8 aq[2];
#pragma unroll
  for (int hh = 0; hh < 2; ++hh)
    aq[hh] = *(const bf16x8*)&qs[(16 * rw + m) * QK_STRIDE + 32 * (2 * hp + hh) + q8];

  float gate[4][4], ssum[4][4];
  {
    float qd_r[4], kd_c[4];
#pragma unroll
    for (int r = 0; r < 4; ++r) qd_r[r] = qd_s[16 * rw + 4 * q + r];
#pragma unroll
    for (int nt = 0; nt < 4; ++nt) kd_c[nt] = kd_s[16 * nt + m];
#pragma unroll
    for (int nt = 0; nt < 4; ++nt)
#pragma unroll
      for (int r = 0; r < 4; ++r) {
        float t = qd_r[r] * kd_c[nt];
        gate[nt][r] = 1.f / (1.f + __expf(-t));
        ssum[nt][r] = 0.f;
      }
  }
  __syncthreads();   // S3 (qs now dead -> at overlay live; oc writable)

  if (hp == 0) {     // zero outcat pad cols 256..287 for rows 16rw..16rw+15
    bf16x8 z = {0, 0, 0, 0, 0, 0, 0, 0};
    *(bf16x8*)&oc[(16 * rw + m) * OC_STRIDE + 256 + q8] = z;
  }

  short* atw = (short*)(smem + QS_OFF) + w * (16 * AT_STRIDE);

#pragma unroll
  for (int hh = 0; hh < 2; ++hh) {
    int h = 2 * hp + hh;
    f32x4 sv[4];
#pragma unroll
    for (int nt = 0; nt < 4; ++nt) {
      bf16x8 bk = *(const bf16x8*)&ks[(16 * nt + m) * QK_STRIDE + 32 * h + q8];
      f32x4 z = {0.f, 0.f, 0.f, 0.f};
      sv[nt] = mfma16(aq[hh], bk, z);
    }
    float sm[4][4], mx[4], sum[4];
#pragma unroll
    for (int r = 0; r < 4; ++r) mx[r] = -3.4e38f;
#pragma unroll
    for (int nt = 0; nt < 4; ++nt)
#pragma unroll
      for (int r = 0; r < 4; ++r) {
        float s = sv[nt][r] * gate[nt][r];
        ssum[nt][r] += s;
        sm[nt][r] = s;
        mx[r] = fmaxf(mx[r], s);
      }
#pragma unroll
    for (int r = 0; r < 4; ++r) {
#pragma unroll
      for (int msk = 1; msk < 16; msk <<= 1)
        mx[r] = fmaxf(mx[r], __shfl_xor(mx[r], msk));
      sum[r] = 0.f;
    }
#pragma unroll
    for (int nt = 0; nt < 4; ++nt)
#pragma unroll
      for (int r = 0; r < 4; ++r) {
        float p = __expf(sm[nt][r] - mx[r]);
        sm[nt][r] = p;
        sum[r] += p;
      }
#pragma unroll
    for (int r = 0; r < 4; ++r) {
#pragma unroll
      for (int msk = 1; msk < 16; msk <<= 1)
        sum[r] += __shfl_xor(sum[r], msk);
      sum[r] = 1.f / sum[r];
    }
#pragma unroll
    for (int nt = 0; nt < 4; ++nt)
#pragma unroll
      for (int r = 0; r < 4; ++r)
        atw[(4 * q + r) * AT_STRIDE + 16 * nt + m] = f2b(sm[nt][r] * sum[r]);

    // A-frags of attn (wave-private LDS round trip; b64-aligned stride 68)
    s16x4 l0 = *(const s16x4*)&atw[m * AT_STRIDE + q8];
    s16x4 l1 = *(const s16x4*)&atw[m * AT_STRIDE + q8 + 4];
    s16x4 l2 = *(const s16x4*)&atw[m * AT_STRIDE + 32 + q8];
    s16x4 l3 = *(const s16x4*)&atw[m * AT_STRIDE + 32 + q8 + 4];
    bf16x8 a0, a1;
#pragma unroll
    for (int j = 0; j < 4; ++j) { a0[j] = l0[j]; a0[4 + j] = l1[j]; a1[j] = l2[j]; a1[4 + j] = l3[j]; }

#pragma unroll
    for (int ntp = 0; ntp < 2; ++ntp) {
      bf16x8 bv0 = *(const bf16x8*)&vs[(((2 * h + ntp) * 2) + 0) * 512 + lane * 8];
      bf16x8 bv1 = *(const bf16x8*)&vs[(((2 * h + ntp) * 2) + 1) * 512 + lane * 8];
      f32x4 o = {0.f, 0.f, 0.f, 0.f};
      o = mfma16(a0, bv0, o);
      o = mfma16(a1, bv1, o);
#pragma unroll
      for (int r = 0; r < 4; ++r)
        oc[(16 * rw + 4 * q + r) * OC_STRIDE + 32 * h + 16 * ntp + m] = f2b(o[r]);
    }
  }

  // head-sum reduction across the 4 hp-waves sharing rw
#pragma unroll
  for (int nt = 0; nt < 4; ++nt)
#pragma unroll
    for (int r = 0; r < 4; ++r)
      atomicAdd(&dsum[(16 * rw + 4 * q + r) * DS_STRIDE + 16 * nt + m], ssum[nt][r]);
  __syncthreads();   // S5

  if (hp == 0) {     // attn_d softmax + out_d for rows 16rw..16rw+15
    float sd[4][4], mx[4], sum[4];
#pragma unroll
    for (int nt = 0; nt < 4; ++nt)
#pragma unroll
      for (int r = 0; r < 4; ++r)
        sd[nt][r] = dsum[(16 * rw + 4 * q + r) * DS_STRIDE + 16 * nt + m];
#pragma unroll
    for (int r = 0; r < 4; ++r) mx[r] = -3.4e38f;
#pragma unroll
    for (int nt = 0; nt < 4; ++nt)
#pragma unroll
      for (int r = 0; r < 4; ++r) mx[r] = fmaxf(mx[r], sd[nt][r]);
#pragma unroll
    for (int r = 0; r < 4; ++r) {
#pragma unroll
      for (int msk = 1; msk < 16; msk <<= 1)
        mx[r] = fmaxf(mx[r], __shfl_xor(mx[r], msk));
      sum[r] = 0.f;
    }
#pragma unroll
    for (int nt = 0; nt < 4; ++nt)
#pragma unroll
      for (int r = 0; r < 4; ++r) {
        sd[nt][r] = __expf(sd[nt][r] - mx[r]);
        sum[r] += sd[nt][r];
      }
#pragma unroll
    for (int r = 0; r < 4; ++r) {
#pragma unroll
      for (int msk = 1; msk < 16; msk <<= 1)
        sum[r] += __shfl_xor(sum[r], msk);
      sum[r] = 1.f / sum[r];
    }
    float vd_c[4];
#pragma unroll
    for (int nt = 0; nt < 4; ++nt) vd_c[nt] = vd_s[16 * nt + m];
    float ov[4] = {0.f, 0.f, 0.f, 0.f};
#pragma unroll
    for (int nt = 0; nt < 4; ++nt)
#pragma unroll
      for (int r = 0; r < 4; ++r) ov[r] += sd[nt][r] * vd_c[nt];
#pragma unroll
    for (int r = 0; r < 4; ++r) {
#pragma unroll
      for (int msk = 1; msk < 16; msk <<= 1)
        ov[r] += __shfl_xor(ov[r], msk);
    }
    if (m == 0) {
#pragma unroll
      for (int r = 0; r < 4; ++r)
        oc[(16 * rw + 4 * q + r) * OC_STRIDE + 256] = f2b(ov[r] * sum[r]);
    }
  }
  __syncthreads();   // S6

  // ---- Phase D: out = outcat[64x288] @ Wout[288x272]. kt-outer; wave w owns nt {w, w+16}.
  {
    f32x4 acc2[2][4];
#pragma unroll
    for (int t = 0; t < 2; ++t)
#pragma unroll
      for (int mt = 0; mt < 4; ++mt) acc2[t][mt] = f32x4{0.f, 0.f, 0.f, 0.f};

    for (int kt = 0; kt < KT; ++kt) {
      bf16x8 ao[4];
#pragma unroll
      for (int mt = 0; mt < 4; ++mt)
        ao[mt] = *(const bf16x8*)&oc[(16 * mt + m) * OC_STRIDE + 32 * kt + q8];
#pragma unroll
      for (int t = 0; t < 2; ++t) {
        int nt = w + 16 * t;
        if (nt < NT_OUT) {
          bf16x8 bw = *(const bf16x8*)(woutp + ((size_t)(kt * NT_OUT + nt) * 64 + lane) * 8);
#pragma unroll
          for (int mt = 0; mt < 4; ++mt)
            acc2[t][mt] = mfma16(ao[mt], bw, acc2[t][mt]);
        }
      }
    }
#pragma unroll
    for (int t = 0; t < 2; ++t) {
      int nt = w + 16 * t;
      if (nt >= NT_OUT) continue;
      int n = 16 * nt + m;
      if (n < D1) {
#pragma unroll
        for (int mt = 0; mt < 4; ++mt)
#pragma unroll
          for (int r = 0; r < 4; ++r)
            out[((size_t)win * NTOK + 16 * mt + 4 * q + r) * D1 + n] = acc2[t][mt][r];
      }
    }
  }
}

extern "C" void kernel_launch(void* const* d_in, const int* in_sizes, int n_in,
                              void* d_out, int out_size, void* d_ws, size_t ws_size,
                              hipStream_t stream) {
  (void)n_in; (void)out_size; (void)ws_size;
  const float* x    = (const float*)d_in[0];
  const float* Wqv  = (const float*)d_in[1];
  const float* Wkv  = (const float*)d_in[2];
  const float* Wvv  = (const float*)d_in[3];
  const float* Wqd  = (const float*)d_in[4];
  const float* Wkd  = (const float*)d_in[5];
  const float* Wvd  = (const float*)d_in[6];
  const float* Wout = (const float*)d_in[7];
  float* out = (float*)d_out;

  short* wcatp = (short*)d_ws;
  short* woutp = wcatp + WCAT_ELEMS;

  int nwin = in_sizes[0] / (NTOK * D1);         // 2048

  hipFuncSetAttribute((const void*)vda_attn, hipFuncAttributeMaxDynamicSharedMemorySize, LDS_SIZE);

  int prep_blocks = (WCAT_ELEMS + WOUT_ELEMS) / 256;   // 1188, exact
  prep_weights<<<prep_blocks, 256, 0, stream>>>(Wqv, Wkv, Wvv, Wqd, Wkd, Wvd, Wout, wcatp, woutp);
  vda_attn<<<nwin, 1024, LDS_SIZE, stream>>>(x, wcatp, woutp, out);
}